// Round 1
// baseline (762.152 us; speedup 1.0000x reference)
//
#include <hip/hip_runtime.h>
#include <math.h>

// VectorQuantizer on MI355X.
// R1: per-lane token ownership. One thread = one token (N=131072).
//  - x[64] in VGPRs, loaded coalesced (lane-consecutive tokens share the
//    spatial dimension, so each c-slice load is a contiguous 64-float run).
//  - Inner loop over K=512 codes: uniform weight-row address -> scalar loads,
//    64 fp32 FMAs per code with 4 accumulators (hide FMA latency at low occ).
//  - Argmin in well-conditioned form s_k = ||w_k||^2 - 2 x.w_k (the +||x||^2
//    constant in the reference cannot change the argmin in fp64, and only
//    adds fp32 rounding noise). Track best/second-best; if gap < EPS, redo
//    the whole scan in fp64 (exactly matches a float64 numpy reference).
//  - Epilogue exploits the reference's preserved layout bug: out and the
//    MSE partner are both flat index n*64+d.
// ws layout (bytes): [0,2048) wsq f32[512] | [2048,4096) counts f32[512]
//                    | [4096,8192) wsqd f64[512] | [8192,8200) sse f64

#define NTOK 131072
#define KCODES 512
#define HW 4096
#define CHW 262144
#define NELEM 8388608
#define EPS_GAP 1.0e-5f

__global__ __launch_bounds__(512) void vq_init(const float* __restrict__ w,
                                               float* __restrict__ wsq,
                                               double* __restrict__ wsqd,
                                               float* __restrict__ counts,
                                               double* __restrict__ sse_acc) {
    int k = threadIdx.x;  // 512 threads, 1 block
    const float* wr = w + (k << 6);
    float a = 0.f;
    double ad = 0.0;
#pragma unroll
    for (int d = 0; d < 64; ++d) {
        float v = wr[d];
        a = fmaf(v, v, a);
        ad = fma((double)v, (double)v, ad);
    }
    wsq[k] = a;
    wsqd[k] = ad;
    counts[k] = 0.f;
    if (k == 0) *sse_acc = 0.0;
}

__global__ __launch_bounds__(256) void vq_main(const float* __restrict__ in,
                                               const float* __restrict__ w,
                                               float* __restrict__ out,
                                               const float* __restrict__ wsq,
                                               const double* __restrict__ wsqd,
                                               float* __restrict__ counts,
                                               double* __restrict__ sse_acc) {
    const int n = blockIdx.x * 256 + threadIdx.x;
    const int b = n >> 12;
    const int sp = n & 4095;

    // Gather this token's 64-dim feature vector (stride HW between channels;
    // per-instruction the wave's 64 lanes hit 64 contiguous floats).
    const float* xin = in + b * CHW + sp;
    float x[64];
#pragma unroll
    for (int c = 0; c < 64; ++c) x[c] = xin[c * HW];

    // fp32 scan over all codes, tracking best and runner-up values.
    float best = 3.0e38f, best2 = 3.0e38f;
    int bidx = 0;
#pragma unroll 1
    for (int k = 0; k < KCODES; ++k) {
        const float* wr = w + (k << 6);
        float a0 = 0.f, a1 = 0.f, a2 = 0.f, a3 = 0.f;
#pragma unroll
        for (int d = 0; d < 64; d += 4) {
            a0 = fmaf(x[d + 0], wr[d + 0], a0);
            a1 = fmaf(x[d + 1], wr[d + 1], a1);
            a2 = fmaf(x[d + 2], wr[d + 2], a2);
            a3 = fmaf(x[d + 3], wr[d + 3], a3);
        }
        float acc = (a0 + a1) + (a2 + a3);
        float s = fmaf(-2.f, acc, wsq[k]);
        bool lt = (s < best);
        best2 = lt ? best : (s < best2 ? s : best2);
        best = lt ? s : best;
        bidx = lt ? k : bidx;
    }

    // If runner-up is within fp32 error reach of best, resolve in fp64
    // (matches a float64 reference argmin exactly; ties -> lowest index).
    if (best2 - best < EPS_GAP) {
        double db = 1.0e300;
        int di = 0;
#pragma unroll 1
        for (int k = 0; k < KCODES; ++k) {
            const float* wr = w + (k << 6);
            double acc = 0.0;
#pragma unroll
            for (int d = 0; d < 64; ++d)
                acc = fma((double)x[d], (double)wr[d], acc);
            double s = fma(-2.0, acc, wsqd[k]);
            if (s < db) { db = s; di = k; }
        }
        bidx = di;
    }

    // Epilogue: write quantized row (token-major == reference's buggy NCHW
    // view) and accumulate SSE against the same flat indices of the input.
    const float* wq = w + (bidx << 6);
    const float* xi = in + (n << 6);
    float* op = out + (n << 6);
    float sse = 0.f;
#pragma unroll
    for (int d = 0; d < 64; d += 4) {
        float4 q = *(const float4*)(wq + d);
        float4 v = *(const float4*)(xi + d);
        *(float4*)(op + d) = q;
        float e0 = q.x - v.x, e1 = q.y - v.y, e2 = q.z - v.z, e3 = q.w - v.w;
        sse = fmaf(e0, e0, sse);
        sse = fmaf(e1, e1, sse);
        sse = fmaf(e2, e2, sse);
        sse = fmaf(e3, e3, sse);
    }
    atomicAdd(&counts[bidx], 1.0f);

    // wave-level reduction of sse, one fp64 atomic per wave
#pragma unroll
    for (int off = 32; off > 0; off >>= 1) sse += __shfl_down(sse, off, 64);
    if ((threadIdx.x & 63) == 0) atomicAdd(sse_acc, (double)sse);
}

__global__ __launch_bounds__(512) void vq_final(const float* __restrict__ counts,
                                                const double* __restrict__ sse_acc,
                                                float* __restrict__ out) {
    __shared__ double red[512];
    int k = threadIdx.x;  // 512 threads, 1 block
    double p = (double)counts[k] / (double)NTOK;
    red[k] = p * log(p + 1e-10);
    __syncthreads();
#pragma unroll
    for (int s = 256; s > 0; s >>= 1) {
        if (k < s) red[k] += red[k + s];
        __syncthreads();
    }
    if (k == 0) {
        out[NELEM] = (float)((*sse_acc / (double)NELEM) * 1.25);
        out[NELEM + 1] = (float)exp(-red[0]);
    }
}

extern "C" void kernel_launch(void* const* d_in, const int* in_sizes, int n_in,
                              void* d_out, int out_size, void* d_ws, size_t ws_size,
                              hipStream_t stream) {
    const float* in = (const float*)d_in[0];
    const float* w = (const float*)d_in[1];
    float* out = (float*)d_out;

    char* ws = (char*)d_ws;
    float* wsq = (float*)(ws + 0);
    float* counts = (float*)(ws + 2048);
    double* wsqd = (double*)(ws + 4096);
    double* sse_acc = (double*)(ws + 8192);

    vq_init<<<1, 512, 0, stream>>>(w, wsq, wsqd, counts, sse_acc);
    vq_main<<<NTOK / 256, 256, 0, stream>>>(in, w, out, wsq, wsqd, counts, sse_acc);
    vq_final<<<1, 512, 0, stream>>>(counts, sse_acc, out);
}

// Round 2
// 194.393 us; speedup vs baseline: 3.9207x; 3.9207x over previous
//
#include <hip/hip_runtime.h>
#include <math.h>

// VectorQuantizer on MI355X — R2: MFMA split-bf16 distance scan.
// S[n,k] = wsq[k] - 2*x_n.w_k computed as 3-pass bf16 MFMA (hh + lh + hl),
// error ~1e-7 (same near-tie flip profile as the passing R1 fp32 kernel).
// 256 blocks x 1024 thr (16 waves) = 1 block/CU, exact 256-CU fill.
// Block stages Wh/Wl (bf16, 72-elem padded rows) + wsq in 151.5 KB LDS once.
// Wave owns 32 tokens; X A-frags built once from the NCHW gather and kept in
// VGPRs for all 16 code-tiles (fixes R1's per-iteration load-latency bound).
// mfma_f32_16x16x32_bf16: A[m=lane&15][k=(lane>>4)*8+j] (m120-verified),
// C/D col=lane&15(code), row=(lane>>4)*4+reg(token) (m89/m91-verified).
// ws: [0,2048) counts f32[512] | [2048,2056) sse f64

#define NTOK 131072
#define KCODES 512
#define HW 4096
#define CHW 262144
#define NELEM 8388608
#define WPAD 72  // padded LDS row (bf16 elems): 144 B stride, conflict-free b128

typedef __attribute__((ext_vector_type(8))) short short8;
typedef __attribute__((ext_vector_type(4))) float f32x4;

static __device__ __forceinline__ unsigned short f2bf(float f) {
    unsigned u = __float_as_uint(f);
    unsigned r = u + 0x7FFFu + ((u >> 16) & 1u);  // RNE
    return (unsigned short)(r >> 16);
}
static __device__ __forceinline__ float bf2f(unsigned short h) {
    return __uint_as_float(((unsigned)h) << 16);
}

__global__ __launch_bounds__(512) void vq_zero(float* counts, double* sse) {
    counts[threadIdx.x] = 0.f;
    if (threadIdx.x == 0) *sse = 0.0;
}

__global__ __launch_bounds__(1024) void vq_mfma(const float* __restrict__ in,
                                                const float* __restrict__ w,
                                                float* __restrict__ out,
                                                float* __restrict__ counts,
                                                double* __restrict__ sse_acc) {
    __shared__ unsigned short whs[KCODES * WPAD];  // 73728 B
    __shared__ unsigned short wls[KCODES * WPAD];  // 73728 B
    __shared__ float wsqs[KCODES];                 // 2048 B
    __shared__ int idxbuf[16 * 32];                // 2048 B

    const int tid = threadIdx.x;

    // ---- stage W -> LDS as bf16 hi/lo (thread t: row t>>1, half t&1) ----
    {
        const int r = tid >> 1, hh = tid & 1;
        const float* wr = w + r * 64 + hh * 32;
        unsigned short* dh = whs + r * WPAD + hh * 32;
        unsigned short* dl = wls + r * WPAD + hh * 32;
#pragma unroll
        for (int i = 0; i < 32; i += 4) {
            float4 v = *(const float4*)(wr + i);
            unsigned short h0 = f2bf(v.x), h1 = f2bf(v.y), h2 = f2bf(v.z), h3 = f2bf(v.w);
            dh[i + 0] = h0; dh[i + 1] = h1; dh[i + 2] = h2; dh[i + 3] = h3;
            dl[i + 0] = f2bf(v.x - bf2f(h0));
            dl[i + 1] = f2bf(v.y - bf2f(h1));
            dl[i + 2] = f2bf(v.z - bf2f(h2));
            dl[i + 3] = f2bf(v.w - bf2f(h3));
        }
    }
    if (tid < KCODES) {  // wsq[k] = sum_d w[k][d]^2 in fp32
        const float* wr = w + tid * 64;
        float s = 0.f;
#pragma unroll
        for (int i = 0; i < 64; ++i) s = fmaf(wr[i], wr[i], s);
        wsqs[tid] = s;
    }
    __syncthreads();

    const int lane = tid & 63;
    const int wv = tid >> 6;
    const int col = lane & 15;   // C/D col (code within tile); A row (token)
    const int quad = lane >> 4;  // 0..3
    const int n0 = blockIdx.x * 512 + wv * 32;

    // ---- build A-frags (X, scaled by -2) once; 2 subtiles x 2 k-chunks ----
    short8 ah[2][2], al[2][2];
#pragma unroll
    for (int sub = 0; sub < 2; ++sub) {
        const int n = n0 + sub * 16 + col;
        const float* base = in + (n >> 12) * CHW + (n & 4095);
#pragma unroll
        for (int c = 0; c < 2; ++c) {
#pragma unroll
            for (int j = 0; j < 8; ++j) {
                const int k = c * 32 + quad * 8 + j;
                float xs = -2.f * base[k * HW];
                unsigned short h = f2bf(xs);
                ah[sub][c][j] = (short)h;
                al[sub][c][j] = (short)f2bf(xs - bf2f(h));
            }
        }
    }

    float runval[2][4];
    int runidx[2][4];
#pragma unroll
    for (int sub = 0; sub < 2; ++sub)
#pragma unroll
        for (int r = 0; r < 4; ++r) { runval[sub][r] = 3.0e38f; runidx[sub][r] = 0; }

    // ---- scan 32 code-tiles of 16 codes ----
#pragma unroll 1
    for (int t = 0; t < 32; ++t) {
        const unsigned short* rowh = whs + (t * 16 + col) * WPAD + quad * 8;
        const unsigned short* rowl = wls + (t * 16 + col) * WPAD + quad * 8;
        short8 bh0 = *(const short8*)(rowh);
        short8 bh1 = *(const short8*)(rowh + 32);
        short8 bl0 = *(const short8*)(rowl);
        short8 bl1 = *(const short8*)(rowl + 32);
        const float wsqv = wsqs[t * 16 + col];
        const int idxc = t * 16 + col;
#pragma unroll
        for (int sub = 0; sub < 2; ++sub) {
            f32x4 acc = {0.f, 0.f, 0.f, 0.f};
            acc = __builtin_amdgcn_mfma_f32_16x16x32_bf16(ah[sub][0], bh0, acc, 0, 0, 0);
            acc = __builtin_amdgcn_mfma_f32_16x16x32_bf16(ah[sub][1], bh1, acc, 0, 0, 0);
            acc = __builtin_amdgcn_mfma_f32_16x16x32_bf16(al[sub][0], bh0, acc, 0, 0, 0);
            acc = __builtin_amdgcn_mfma_f32_16x16x32_bf16(al[sub][1], bh1, acc, 0, 0, 0);
            acc = __builtin_amdgcn_mfma_f32_16x16x32_bf16(ah[sub][0], bl0, acc, 0, 0, 0);
            acc = __builtin_amdgcn_mfma_f32_16x16x32_bf16(ah[sub][1], bl1, acc, 0, 0, 0);
#pragma unroll
            for (int r = 0; r < 4; ++r) {
                const float cand = acc[r] + wsqv;
                const bool lt = cand < runval[sub][r];
                runval[sub][r] = lt ? cand : runval[sub][r];
                runidx[sub][r] = lt ? idxc : runidx[sub][r];
            }
        }
    }

    // ---- cross-lane argmin over the 16 cols (xor on lane bits 0..3) ----
#pragma unroll
    for (int s = 1; s < 16; s <<= 1) {
#pragma unroll
        for (int sub = 0; sub < 2; ++sub)
#pragma unroll
            for (int r = 0; r < 4; ++r) {
                const float pv = __shfl_xor(runval[sub][r], s, 64);
                const int pi = __shfl_xor(runidx[sub][r], s, 64);
                const bool take = (pv < runval[sub][r]) ||
                                  (pv == runval[sub][r] && pi < runidx[sub][r]);
                runval[sub][r] = take ? pv : runval[sub][r];
                runidx[sub][r] = take ? pi : runidx[sub][r];
            }
    }
    if (col == 0) {  // one lane per quad writes its 4 token-rows (x2 subtiles)
#pragma unroll
        for (int sub = 0; sub < 2; ++sub)
#pragma unroll
            for (int r = 0; r < 4; ++r)
                idxbuf[wv * 32 + sub * 16 + quad * 4 + r] = runidx[sub][r];
    }
    __syncthreads();

    if (lane < 32) atomicAdd(&counts[idxbuf[wv * 32 + lane]], 1.0f);

    // ---- fused epilogue: lane handles token (lane>>1), half (lane&1) ----
    {
        const int tt = lane >> 1, hh = lane & 1;
        const int n = n0 + tt;
        const int bidx = idxbuf[wv * 32 + tt];
        const uint4* qh4 = (const uint4*)(whs + bidx * WPAD + hh * 32);
        const uint4* ql4 = (const uint4*)(wls + bidx * WPAD + hh * 32);
        const float* xp = in + n * 64 + hh * 32;  // NCHW-flat (layout-bug pairing)
        float* op = out + n * 64 + hh * 32;
        float sse = 0.f;
#pragma unroll
        for (int i8 = 0; i8 < 4; ++i8) {
            const uint4 hb = qh4[i8];
            const uint4 lb = ql4[i8];
            const unsigned hu[4] = {hb.x, hb.y, hb.z, hb.w};
            const unsigned lu[4] = {lb.x, lb.y, lb.z, lb.w};
#pragma unroll
            for (int p = 0; p < 4; ++p) {
                const float q0 = __uint_as_float(hu[p] << 16) + __uint_as_float(lu[p] << 16);
                const float q1 = __uint_as_float(hu[p] & 0xFFFF0000u) +
                                 __uint_as_float(lu[p] & 0xFFFF0000u);
                const int e = i8 * 8 + p * 2;
                const float x0 = xp[e], x1 = xp[e + 1];
                op[e] = q0;
                op[e + 1] = q1;
                sse = fmaf(q0 - x0, q0 - x0, sse);
                sse = fmaf(q1 - x1, q1 - x1, sse);
            }
        }
#pragma unroll
        for (int off = 32; off > 0; off >>= 1) sse += __shfl_down(sse, off, 64);
        if (lane == 0) atomicAdd(sse_acc, (double)sse);
    }
}

__global__ __launch_bounds__(512) void vq_final(const float* __restrict__ counts,
                                                const double* __restrict__ sse_acc,
                                                float* __restrict__ out) {
    __shared__ double red[512];
    const int k = threadIdx.x;
    const double p = (double)counts[k] / (double)NTOK;
    red[k] = p * log(p + 1e-10);
    __syncthreads();
#pragma unroll
    for (int s = 256; s > 0; s >>= 1) {
        if (k < s) red[k] += red[k + s];
        __syncthreads();
    }
    if (k == 0) {
        out[NELEM] = (float)((*sse_acc / (double)NELEM) * 1.25);
        out[NELEM + 1] = (float)exp(-red[0]);
    }
}

extern "C" void kernel_launch(void* const* d_in, const int* in_sizes, int n_in,
                              void* d_out, int out_size, void* d_ws, size_t ws_size,
                              hipStream_t stream) {
    const float* in = (const float*)d_in[0];
    const float* w = (const float*)d_in[1];
    float* out = (float*)d_out;

    char* ws = (char*)d_ws;
    float* counts = (float*)(ws + 0);
    double* sse_acc = (double*)(ws + 2048);

    vq_zero<<<1, 512, 0, stream>>>(counts, sse_acc);
    vq_mfma<<<256, 1024, 0, stream>>>(in, w, out, counts, sse_acc);
    vq_final<<<1, 512, 0, stream>>>(counts, sse_acc, out);
}